// Round 7
// baseline (262.997 us; speedup 1.0000x reference)
//
#include <hip/hip_runtime.h>

// B=4, N=10, C=256, Lq=Ls=1024, K=5, G=2.  TQ=64, TS=32.  fp16 MFMA path.
#define CQ_ELEMS (4 * 256 * 1024)
#define CS_ELEMS (10 * 256 * 1024)
#define OUT2_OFF 2097152

typedef __attribute__((ext_vector_type(8))) _Float16 f16x8;
typedef __attribute__((ext_vector_type(4))) float f32x4;

// ws layout (bytes): [0..255] float means[2];
//   Sh[n][s][c] fp16, Sv[n][c][s] fp16, Qt[b][q][c] fp16
#define WS_SH 256
#define SH_ELEMS (10 * 1024 * 256)
#define SV_ELEMS (10 * 256 * 1024)

// direct global->LDS DMA, 16 B per lane; LDS dest = wave-uniform base + lane*16
__device__ __forceinline__ void gload_lds16(const unsigned short* g, unsigned short* l) {
    __builtin_amdgcn_global_load_lds(
        (const __attribute__((address_space(1))) void*)g,
        (__attribute__((address_space(3))) void*)l, 16, 0, 0);
}

// ---------------------------------------------------------------------------
__global__ __launch_bounds__(256) void means_kernel(const float* __restrict__ q,
                                                    const float* __restrict__ s,
                                                    float* __restrict__ ws) {
    const int tid = blockIdx.x * 256 + threadIdx.x;
    const int stride = gridDim.x * 256;
    float sq = 0.f, ss = 0.f;
    const float4* q4 = (const float4*)q;
    const float4* s4 = (const float4*)s;
    for (int i = tid; i < CQ_ELEMS / 4; i += stride) {
        float4 v = q4[i];
        sq += (v.x + v.y) + (v.z + v.w);
    }
    for (int i = tid; i < CS_ELEMS / 4; i += stride) {
        float4 v = s4[i];
        ss += (v.x + v.y) + (v.z + v.w);
    }
#pragma unroll
    for (int off = 32; off > 0; off >>= 1) {
        sq += __shfl_down(sq, off, 64);
        ss += __shfl_down(ss, off, 64);
    }
    __shared__ float redq[4], reds[4];
    const int lane = threadIdx.x & 63, wid = threadIdx.x >> 6;
    if (lane == 0) { redq[wid] = sq; reds[wid] = ss; }
    __syncthreads();
    if (threadIdx.x == 0) {
        atomicAdd(&ws[0], (redq[0] + redq[1]) + (redq[2] + redq[3]));
        atomicAdd(&ws[1], (reds[0] + reds[1]) + (reds[2] + reds[3]));
    }
}

// ---------------------------------------------------------------------------
// Centered fp16 conversion.  z<10: S -> Sv [c][s] + Sh [s][c] + zero out2.
// z>=10: Q -> q_out (fp32, both g-copies) + Qt [q][c].
// ---------------------------------------------------------------------------
__global__ __launch_bounds__(256) void convert_kernel(const float* __restrict__ Q,
                                                      const float* __restrict__ S,
                                                      const float* __restrict__ ws,
                                                      unsigned short* __restrict__ sh,
                                                      unsigned short* __restrict__ sv,
                                                      unsigned short* __restrict__ qt,
                                                      float* __restrict__ out) {
    __shared__ unsigned short Th[32][40];
    const int t = threadIdx.x;
    const int x0 = blockIdx.x << 5;   // s (or q) tile base
    const int c0 = blockIdx.y << 5;   // c tile base
    const int z = blockIdx.z;

    const int cl = t >> 3, x4 = (t & 7) << 2;

    if (z < 10) {
        const int n = z;
        const float ms = ws[1] * (1.0f / (float)CS_ELEMS);
        float4 v = *(const float4*)(S + ((size_t)(n * 256 + c0 + cl)) * 1024 + x0 + x4);
        float x[4] = {v.x - ms, v.y - ms, v.z - ms, v.w - ms};
        unsigned short hb[4];
#pragma unroll
        for (int j = 0; j < 4; ++j) {
            _Float16 h = (_Float16)x[j];
            hb[j] = __builtin_bit_cast(unsigned short, h);
            Th[cl][x4 + j] = hb[j];
        }
        *(ushort4*)(sv + ((size_t)(n * 256 + c0 + cl)) * 1024 + x0 + x4) =
            make_ushort4(hb[0], hb[1], hb[2], hb[3]);
        // zero the atomically-accumulated 'aligned' half of d_out (8 MB over 2560 blocks)
        {
            const int lin = (z * 8 + blockIdx.y) * 32 + blockIdx.x;
            const int gid = lin * 256 + t;
            if (gid < 524288) ((int4*)(out + OUT2_OFF))[gid] = make_int4(0, 0, 0, 0);
        }
        __syncthreads();
        const int sl = t >> 3, c4 = (t & 7) << 2;
        *(ushort4*)(sh + ((size_t)(n * 1024 + x0 + sl)) * 256 + c0 + c4) =
            make_ushort4(Th[c4 + 0][sl], Th[c4 + 1][sl], Th[c4 + 2][sl], Th[c4 + 3][sl]);
    } else {
        const int b = z - 10;
        const float mq = ws[0] * (1.0f / (float)CQ_ELEMS);
        float4 v = *(const float4*)(Q + ((size_t)(b * 256 + c0 + cl)) * 1024 + x0 + x4);
        v.x -= mq; v.y -= mq; v.z -= mq; v.w -= mq;
        float* o = out + ((size_t)(b * 2) * 256 + (c0 + cl)) * 1024 + x0 + x4;
        *(float4*)o = v;
        *(float4*)(o + 256 * 1024) = v;
        float x[4] = {v.x, v.y, v.z, v.w};
#pragma unroll
        for (int j = 0; j < 4; ++j) {
            _Float16 h = (_Float16)x[j];
            Th[cl][x4 + j] = __builtin_bit_cast(unsigned short, h);
        }
        __syncthreads();
        const int ql = t >> 3, c4 = (t & 7) << 2;
        *(ushort4*)(qt + ((size_t)(b * 1024 + x0 + ql)) * 256 + c0 + c4) =
            make_ushort4(Th[c4 + 0][ql], Th[c4 + 1][ql], Th[c4 + 2][ql], Th[c4 + 3][ql]);
    }
}

// ---------------------------------------------------------------------------
// Fused flash attention, fp16 MFMA, DMA double-buffer, ONE barrier per step.
// Block = (64-q tile, bn pair), 4 waves.  Wave w owns q rows 16w..16w+15 for
// BOTH QK^T and PV (P B-frag comes from the wave's own pb rows -> no mid-step
// barrier; alpha/l are wave-local via tiny LDS arrays).
// s1[buf] (16 KB each): frag-major; slot16 = (f*2+nt)*64 + quad*16 + l16 holds
//   Sh[s0+2*l16+nt][f*32+quad*8..+7].  Frag reads consecutive-lane -> cf.
// s2[buf]: slot16 p holds V^T[c=p>>2][chunk=(p&3)^((c>>2)&3)]; read 2-way (free).
// pb [q][s] 80 B rows, wave-local regions.
// DMA for step i+1 issues right after step i's sync; drained at step i+1's
// sync -> full step of latency hiding.  No cross-barrier register arrays
// (R4/R5: those spill to scratch).
// ---------------------------------------------------------------------------
union __align__(16) SMem {
    struct {
        unsigned short s1[2][8192];  // 32 KB
        unsigned short s2[2][8192];  // 32 KB
        unsigned short pb[64][40];   // 5 KB
    } st;
    float epi[256][68];              // 69632 B, aliases st at epilogue
};

__global__ __launch_bounds__(256, 2) void attn_kernel(const unsigned short* __restrict__ qt,
                                                      const unsigned short* __restrict__ sh,
                                                      const unsigned short* __restrict__ sv,
                                                      float* __restrict__ out) {
    __shared__ SMem sm;
    __shared__ float aw[64];   // per-step alpha, wave-local use
    __shared__ float lw[64];   // final l, wave-local use

    const int t = threadIdx.x;
    const int w = t >> 6;
    const int lane = t & 63;
    const int quad = lane >> 4;
    const int l16 = lane & 15;

    const int q0 = blockIdx.x << 6;   // 16 q-tiles
    const int bn = blockIdx.y;        // 40
    const int b = bn / 10;
    const int n = bn - b * 10;
    const int g = n / 5;

    const unsigned short* __restrict__ Shn = sh + (size_t)n * (1024 * 256);
    const unsigned short* __restrict__ Svn = sv + (size_t)n * (256 * 1024);

    // ---- Q A-frags: wave w owns q rows q0+16w .. +15 ----
    f16x8 qf[8];
    {
        const unsigned short* qp = qt + (size_t)(b * 1024 + q0 + 16 * w + l16) * 256 + quad * 8;
#pragma unroll
        for (int f = 0; f < 8; ++f)
            qf[f] = *(const f16x8*)(qp + f * 32);
    }

    f32x4 O[16];   // O^T: c = 16mt+4quad+r, q = 16w+l16
#pragma unroll
    for (int mt = 0; mt < 16; ++mt) O[mt] = (f32x4){0.f, 0.f, 0.f, 0.f};

    float m_run[4], l_run[4];
#pragma unroll
    for (int r = 0; r < 4; ++r) { m_run[r] = -1e30f; l_run[r] = 0.f; }

    // ---- DMA staging for one step into buffer `buf` ----
#define STAGE(s0_, buf_)                                                                   \
    {                                                                                      \
        const int s0v = (s0_);                                                             \
        _Pragma("unroll")                                                                  \
        for (int j = 0; j < 4; ++j) {                                                      \
            const int fidx = 4 * w + j;                                                    \
            const unsigned short* g1 = Shn +                                               \
                (size_t)(s0v + 2 * l16 + (fidx & 1)) * 256 + (fidx >> 1) * 32 + quad * 8;  \
            gload_lds16(g1, &sm.st.s1[buf_][fidx * 512]);                                  \
            const unsigned short* g2 = Svn +                                               \
                (size_t)(w * 64 + j * 16 + (lane >> 2)) * 1024 + s0v +                     \
                ((lane & 3) ^ (lane >> 4)) * 8;                                            \
            gload_lds16(g2, &sm.st.s2[buf_][fidx * 512]);                                  \
        }                                                                                  \
    }

    STAGE(0, 0);

    for (int s0i = 0; s0i < 32; ++s0i) {
        const int cur = s0i & 1;
        __syncthreads();   // drains DMA into buf[cur]; all waves done with buf[cur^1] reads

        if (s0i < 31) STAGE((s0i + 1) << 5, cur ^ 1);   // in flight until next sync

        // ---- QK^T: sim[16q x 32s], q rows 16w+4quad+r ----
        f32x4 sim0 = (f32x4){0.f, 0.f, 0.f, 0.f};
        f32x4 sim1 = (f32x4){0.f, 0.f, 0.f, 0.f};
#pragma unroll
        for (int f = 0; f < 8; ++f) {
            const unsigned short* base = &sm.st.s1[cur][f * 1024 + quad * 128 + l16 * 8];
            f16x8 b0 = *(const f16x8*)base;           // nt=0: true s = 2*l16
            f16x8 b1 = *(const f16x8*)(base + 512);   // nt=1: true s = 2*l16+1
            sim0 = __builtin_amdgcn_mfma_f32_16x16x32_f16(qf[f], b0, sim0, 0, 0, 0);
            sim1 = __builtin_amdgcn_mfma_f32_16x16x32_f16(qf[f], b1, sim1, 0, 0, 0);
        }

        // ---- online softmax (reduce over the 16 l16 lanes) ----
        float rowmax[4];
#pragma unroll
        for (int r = 0; r < 4; ++r) rowmax[r] = fmaxf(sim0[r], sim1[r]);
#pragma unroll
        for (int off = 1; off <= 8; off <<= 1)
#pragma unroll
            for (int r = 0; r < 4; ++r)
                rowmax[r] = fmaxf(rowmax[r], __shfl_xor(rowmax[r], off, 64));

        float al[4], rs[4], pv0[4], pv1[4];
#pragma unroll
        for (int r = 0; r < 4; ++r) {
            const float mn = fmaxf(m_run[r], rowmax[r]);
            al[r] = __expf(m_run[r] - mn);
            m_run[r] = mn;
            pv0[r] = __expf(sim0[r] - mn);
            pv1[r] = __expf(sim1[r] - mn);
            rs[r] = pv0[r] + pv1[r];
        }
#pragma unroll
        for (int off = 1; off <= 8; off <<= 1)
#pragma unroll
            for (int r = 0; r < 4; ++r) rs[r] += __shfl_xor(rs[r], off, 64);
#pragma unroll
        for (int r = 0; r < 4; ++r) l_run[r] = l_run[r] * al[r] + rs[r];

        // ---- publish P + alpha to WAVE-LOCAL LDS (no barrier: same-wave dep) ----
#pragma unroll
        for (int r = 0; r < 4; ++r) {
            union { _Float16 h[2]; unsigned u; } pk;
            pk.h[0] = (_Float16)pv0[r];
            pk.h[1] = (_Float16)pv1[r];
            *(unsigned*)&sm.st.pb[16 * w + 4 * quad + r][l16 * 2] = pk.u;
        }
        if (l16 == 0) {
#pragma unroll
            for (int r = 0; r < 4; ++r) aw[16 * w + 4 * quad + r] = al[r];
        }

        // ---- rescale O^T by own-row alpha, then O^T += V^T * P^T ----
        const float a = aw[16 * w + l16];
#pragma unroll
        for (int mt = 0; mt < 16; ++mt) {
            O[mt][0] *= a; O[mt][1] *= a; O[mt][2] *= a; O[mt][3] *= a;
        }
        const f16x8 pf = *(const f16x8*)&sm.st.pb[16 * w + l16][quad * 8];
#pragma unroll
        for (int mt = 0; mt < 16; ++mt) {
            const int c = 16 * mt + l16;
            const int p = c * 4 + (quad ^ (l16 >> 2));
            f16x8 vf = *(const f16x8*)&sm.st.s2[cur][p * 8];
            O[mt] = __builtin_amdgcn_mfma_f32_16x16x32_f16(vf, pf, O[mt], 0, 0, 0);
        }
    }

    // ---- epilogue ----
    if (l16 == 0) {
#pragma unroll
        for (int r = 0; r < 4; ++r) lw[16 * w + 4 * quad + r] = l_run[r];
    }
    __syncthreads();   // final PV reads done -> epi may alias st
    const float li = 0.2f / lw[16 * w + l16];

#pragma unroll
    for (int mt = 0; mt < 16; ++mt)
#pragma unroll
        for (int r = 0; r < 4; ++r)
            sm.epi[16 * mt + 4 * quad + r][16 * w + l16] = O[mt][r] * li;
    __syncthreads();

    float* __restrict__ out2 = out + OUT2_OFF + (size_t)((g << 2) + b) * (256 * 1024);
#pragma unroll 4
    for (int i = 0; i < 64; ++i) {
        const int c = i * 4 + w;
        atomicAdd(out2 + (size_t)c * 1024 + q0 + lane, sm.epi[c][lane]);
    }
}

// ---------------------------------------------------------------------------
extern "C" void kernel_launch(void* const* d_in, const int* in_sizes, int n_in,
                              void* d_out, int out_size, void* d_ws, size_t ws_size,
                              hipStream_t stream) {
    const float* q = (const float*)d_in[0];
    const float* s = (const float*)d_in[1];
    float* out = (float*)d_out;
    float* ws = (float*)d_ws;
    unsigned short* sh = (unsigned short*)((char*)d_ws + WS_SH);
    unsigned short* sv = sh + SH_ELEMS;
    unsigned short* qt = sv + SV_ELEMS;

    hipMemsetAsync(d_ws, 0, 2 * sizeof(float), stream);

    means_kernel<<<256, 256, 0, stream>>>(q, s, ws);
    convert_kernel<<<dim3(32, 8, 14), 256, 0, stream>>>(q, s, ws, sh, sv, qt, out);
    attn_kernel<<<dim3(16, 40), 256, 0, stream>>>(qt, sh, sv, out);
}

// Round 8
// 211.702 us; speedup vs baseline: 1.2423x; 1.2423x over previous
//
#include <hip/hip_runtime.h>

// B=4, N=10, C=256, Lq=Ls=1024, K=5, G=2.  TQ=64, TS=32.  fp16 MFMA path.
#define CQ_ELEMS (4 * 256 * 1024)
#define CS_ELEMS (10 * 256 * 1024)
#define OUT2_OFF 2097152

typedef __attribute__((ext_vector_type(8))) _Float16 f16x8;
typedef __attribute__((ext_vector_type(4))) float f32x4;

// ws layout (bytes): [0..255] float means[2];
//   Sh[n][s][c] fp16, Sv[n][c][s] fp16, Qt[b][q][c] fp16
#define WS_SH 256
#define SH_ELEMS (10 * 1024 * 256)
#define SV_ELEMS (10 * 256 * 1024)

// direct global->LDS DMA, 16 B per lane; LDS dest = wave-uniform base + lane*16
__device__ __forceinline__ void gload_lds16(const unsigned short* g, unsigned short* l) {
    __builtin_amdgcn_global_load_lds(
        (const __attribute__((address_space(1))) void*)g,
        (__attribute__((address_space(3))) void*)l, 16, 0, 0);
}

// ---------------------------------------------------------------------------
__global__ __launch_bounds__(256) void means_kernel(const float* __restrict__ q,
                                                    const float* __restrict__ s,
                                                    float* __restrict__ ws) {
    const int tid = blockIdx.x * 256 + threadIdx.x;
    const int stride = gridDim.x * 256;
    float sq = 0.f, ss = 0.f;
    const float4* q4 = (const float4*)q;
    const float4* s4 = (const float4*)s;
    for (int i = tid; i < CQ_ELEMS / 4; i += stride) {
        float4 v = q4[i];
        sq += (v.x + v.y) + (v.z + v.w);
    }
    for (int i = tid; i < CS_ELEMS / 4; i += stride) {
        float4 v = s4[i];
        ss += (v.x + v.y) + (v.z + v.w);
    }
#pragma unroll
    for (int off = 32; off > 0; off >>= 1) {
        sq += __shfl_down(sq, off, 64);
        ss += __shfl_down(ss, off, 64);
    }
    __shared__ float redq[4], reds[4];
    const int lane = threadIdx.x & 63, wid = threadIdx.x >> 6;
    if (lane == 0) { redq[wid] = sq; reds[wid] = ss; }
    __syncthreads();
    if (threadIdx.x == 0) {
        atomicAdd(&ws[0], (redq[0] + redq[1]) + (redq[2] + redq[3]));
        atomicAdd(&ws[1], (reds[0] + reds[1]) + (reds[2] + reds[3]));
    }
}

// ---------------------------------------------------------------------------
// Centered fp16 conversion.  z<10: S -> Sv [c][s] + Sh [s][c] + zero out2.
// z>=10: Q -> q_out (fp32, both g-copies) + Qt [q][c].
// ---------------------------------------------------------------------------
__global__ __launch_bounds__(256) void convert_kernel(const float* __restrict__ Q,
                                                      const float* __restrict__ S,
                                                      const float* __restrict__ ws,
                                                      unsigned short* __restrict__ sh,
                                                      unsigned short* __restrict__ sv,
                                                      unsigned short* __restrict__ qt,
                                                      float* __restrict__ out) {
    __shared__ unsigned short Th[32][40];
    const int t = threadIdx.x;
    const int x0 = blockIdx.x << 5;   // s (or q) tile base
    const int c0 = blockIdx.y << 5;   // c tile base
    const int z = blockIdx.z;

    const int cl = t >> 3, x4 = (t & 7) << 2;

    if (z < 10) {
        const int n = z;
        const float ms = ws[1] * (1.0f / (float)CS_ELEMS);
        float4 v = *(const float4*)(S + ((size_t)(n * 256 + c0 + cl)) * 1024 + x0 + x4);
        float x[4] = {v.x - ms, v.y - ms, v.z - ms, v.w - ms};
        unsigned short hb[4];
#pragma unroll
        for (int j = 0; j < 4; ++j) {
            _Float16 h = (_Float16)x[j];
            hb[j] = __builtin_bit_cast(unsigned short, h);
            Th[cl][x4 + j] = hb[j];
        }
        *(ushort4*)(sv + ((size_t)(n * 256 + c0 + cl)) * 1024 + x0 + x4) =
            make_ushort4(hb[0], hb[1], hb[2], hb[3]);
        // zero the atomically-accumulated 'aligned' half of d_out (8 MB over 2560 blocks)
        {
            const int lin = (z * 8 + blockIdx.y) * 32 + blockIdx.x;
            const int gid = lin * 256 + t;
            if (gid < 524288) ((int4*)(out + OUT2_OFF))[gid] = make_int4(0, 0, 0, 0);
        }
        __syncthreads();
        const int sl = t >> 3, c4 = (t & 7) << 2;
        *(ushort4*)(sh + ((size_t)(n * 1024 + x0 + sl)) * 256 + c0 + c4) =
            make_ushort4(Th[c4 + 0][sl], Th[c4 + 1][sl], Th[c4 + 2][sl], Th[c4 + 3][sl]);
    } else {
        const int b = z - 10;
        const float mq = ws[0] * (1.0f / (float)CQ_ELEMS);
        float4 v = *(const float4*)(Q + ((size_t)(b * 256 + c0 + cl)) * 1024 + x0 + x4);
        v.x -= mq; v.y -= mq; v.z -= mq; v.w -= mq;
        float* o = out + ((size_t)(b * 2) * 256 + (c0 + cl)) * 1024 + x0 + x4;
        *(float4*)o = v;
        *(float4*)(o + 256 * 1024) = v;
        float x[4] = {v.x, v.y, v.z, v.w};
#pragma unroll
        for (int j = 0; j < 4; ++j) {
            _Float16 h = (_Float16)x[j];
            Th[cl][x4 + j] = __builtin_bit_cast(unsigned short, h);
        }
        __syncthreads();
        const int ql = t >> 3, c4 = (t & 7) << 2;
        *(ushort4*)(qt + ((size_t)(b * 1024 + x0 + ql)) * 256 + c0 + c4) =
            make_ushort4(Th[c4 + 0][ql], Th[c4 + 1][ql], Th[c4 + 2][ql], Th[c4 + 3][ql]);
    }
}

// ---------------------------------------------------------------------------
// Fused flash attention, fp16 MFMA.  R6 geometry (3 blocks/CU) with:
//  - s1 DOUBLE-buffered via global_load_lds; DMA for step i+1 issues at the
//    top of step i -> ~QK+softmax worth of latency hiding (the compiler's
//    vmcnt(0)-before-barrier drains it at the P-publish barrier).
//  - s2 ELIMINATED: PV A-frags (V^T) load directly from global Sv (L2-hot,
//    read-only, 4 frags/wave-step) on the otherwise-idle VMEM pipe.
//  - 2 barriers/step (top = DMA drain + buffer protect; P-publish).
// s1 frag-major layout identical to R6 (slot16 = fidx*64 + lane; fidx=2f+nt).
// PV partition cross-wave as R6: wave w owns c-slice 64w..64w+63, all 64 q.
// No cross-barrier read-write register arrays (R4/R5 spill lesson).
// ---------------------------------------------------------------------------
union __align__(16) SMem {
    struct {
        unsigned short s1[2][8192];  // 32 KB, frag-major QK B-tiles (dbuf)
        unsigned short pb[64][40];   // 5 KB, P [q][s] 80 B rows
    } st;
    float epi[2][64][68];            // 34816 B, aliases st at epilogue
};

__global__ __launch_bounds__(256, 3) void attn_kernel(const unsigned short* __restrict__ qt,
                                                      const unsigned short* __restrict__ sh,
                                                      const unsigned short* __restrict__ sv,
                                                      float* __restrict__ out) {
    __shared__ SMem sm;
    __shared__ float aw[64];   // per-step alpha (cross-wave, read after B2)
    __shared__ float lw[64];   // final l

    const int t = threadIdx.x;
    const int w = t >> 6;
    const int lane = t & 63;
    const int quad = lane >> 4;
    const int l16 = lane & 15;

    const int q0 = blockIdx.x << 6;   // 16 q-tiles
    const int bn = blockIdx.y;        // 40
    const int b = bn / 10;
    const int n = bn - b * 10;
    const int g = n / 5;

    const unsigned short* __restrict__ Shn = sh + (size_t)n * (1024 * 256);
    const unsigned short* __restrict__ Svn = sv + (size_t)n * (256 * 1024);

    // ---- Q A-frags: wave w owns q rows q0+16w .. +15 ----
    f16x8 qf[8];
    {
        const unsigned short* qp = qt + (size_t)(b * 1024 + q0 + 16 * w + l16) * 256 + quad * 8;
#pragma unroll
        for (int f = 0; f < 8; ++f)
            qf[f] = *(const f16x8*)(qp + f * 32);
    }

    // V^T frag base pointers (step-invariant): c = 64w + 16mt + l16, chunk quad
    const unsigned short* vbase[4];
#pragma unroll
    for (int mt = 0; mt < 4; ++mt)
        vbase[mt] = Svn + (size_t)(64 * w + 16 * mt + l16) * 1024 + quad * 8;

    f32x4 O[4][4];   // O^T: c = 64w+16mt+4quad+r, q = 16nt+l16
#pragma unroll
    for (int mt = 0; mt < 4; ++mt)
#pragma unroll
        for (int nt = 0; nt < 4; ++nt) O[mt][nt] = (f32x4){0.f, 0.f, 0.f, 0.f};

    float m_run[4], l_run[4];
#pragma unroll
    for (int r = 0; r < 4; ++r) { m_run[r] = -1e30f; l_run[r] = 0.f; }

    // ---- s1 DMA staging for one step into buffer buf_ ----
#define STAGE1(s0_, buf_)                                                                  \
    {                                                                                      \
        const int s0v = (s0_);                                                             \
        _Pragma("unroll")                                                                  \
        for (int j = 0; j < 4; ++j) {                                                      \
            const int fidx = 4 * w + j;                                                    \
            const unsigned short* g1 = Shn +                                               \
                (size_t)(s0v + 2 * l16 + (fidx & 1)) * 256 + (fidx >> 1) * 32 + quad * 8;  \
            gload_lds16(g1, &sm.st.s1[buf_][fidx * 512]);                                  \
        }                                                                                  \
    }

    STAGE1(0, 0);

    for (int s0i = 0; s0i < 32; ++s0i) {
        const int cur = s0i & 1;
        const int s0 = s0i << 5;
        __syncthreads();   // B1: drains DMA into s1[cur]; all reads of s1[cur^1] done

        if (s0i < 31) STAGE1((s0i + 1) << 5, cur ^ 1);   // hidden behind QK+softmax

        // ---- QK^T: sim[16q x 32s], q rows 16w+4quad+r ----
        f32x4 sim0 = (f32x4){0.f, 0.f, 0.f, 0.f};
        f32x4 sim1 = (f32x4){0.f, 0.f, 0.f, 0.f};
#pragma unroll
        for (int f = 0; f < 8; ++f) {
            const unsigned short* base = &sm.st.s1[cur][f * 1024 + quad * 128 + l16 * 8];
            f16x8 b0 = *(const f16x8*)base;           // nt=0: true s = 2*l16
            f16x8 b1 = *(const f16x8*)(base + 512);   // nt=1: true s = 2*l16+1
            sim0 = __builtin_amdgcn_mfma_f32_16x16x32_f16(qf[f], b0, sim0, 0, 0, 0);
            sim1 = __builtin_amdgcn_mfma_f32_16x16x32_f16(qf[f], b1, sim1, 0, 0, 0);
        }

        // ---- online softmax (reduce over the 16 l16 lanes) ----
        float rowmax[4];
#pragma unroll
        for (int r = 0; r < 4; ++r) rowmax[r] = fmaxf(sim0[r], sim1[r]);
#pragma unroll
        for (int off = 1; off <= 8; off <<= 1)
#pragma unroll
            for (int r = 0; r < 4; ++r)
                rowmax[r] = fmaxf(rowmax[r], __shfl_xor(rowmax[r], off, 64));

        float al[4], rs[4], pv0[4], pv1[4];
#pragma unroll
        for (int r = 0; r < 4; ++r) {
            const float mn = fmaxf(m_run[r], rowmax[r]);
            al[r] = __expf(m_run[r] - mn);
            m_run[r] = mn;
            pv0[r] = __expf(sim0[r] - mn);
            pv1[r] = __expf(sim1[r] - mn);
            rs[r] = pv0[r] + pv1[r];
        }
#pragma unroll
        for (int off = 1; off <= 8; off <<= 1)
#pragma unroll
            for (int r = 0; r < 4; ++r) rs[r] += __shfl_xor(rs[r], off, 64);
#pragma unroll
        for (int r = 0; r < 4; ++r) l_run[r] = l_run[r] * al[r] + rs[r];

        // ---- publish P (fp16 pairs, b32) and alpha ----
#pragma unroll
        for (int r = 0; r < 4; ++r) {
            union { _Float16 h[2]; unsigned u; } pk;
            pk.h[0] = (_Float16)pv0[r];
            pk.h[1] = (_Float16)pv1[r];
            *(unsigned*)&sm.st.pb[16 * w + 4 * quad + r][l16 * 2] = pk.u;
        }
        if (l16 == 0) {
#pragma unroll
            for (int r = 0; r < 4; ++r) aw[16 * w + 4 * quad + r] = al[r];
        }
        __syncthreads();   // B2: P/alpha visible to all waves

        // ---- rescale O^T, then O^T += V^T * P^T (V^T frags from GLOBAL) ----
#pragma unroll
        for (int nt = 0; nt < 4; ++nt) {
            const float a = aw[16 * nt + l16];
#pragma unroll
            for (int mt = 0; mt < 4; ++mt) {
                O[mt][nt][0] *= a; O[mt][nt][1] *= a; O[mt][nt][2] *= a; O[mt][nt][3] *= a;
            }
        }
        f16x8 pf[4];
#pragma unroll
        for (int nt = 0; nt < 4; ++nt)
            pf[nt] = *(const f16x8*)&sm.st.pb[16 * nt + l16][quad * 8];
#pragma unroll
        for (int mt = 0; mt < 4; ++mt) {
            f16x8 vf = *(const f16x8*)(vbase[mt] + s0);
#pragma unroll
            for (int nt = 0; nt < 4; ++nt)
                O[mt][nt] = __builtin_amdgcn_mfma_f32_16x16x32_f16(vf, pf[nt], O[mt][nt], 0, 0, 0);
        }
    }

    // ---- epilogue ----
    if (l16 == 0) {
#pragma unroll
        for (int r = 0; r < 4; ++r) lw[16 * w + 4 * quad + r] = l_run[r];
    }
    __syncthreads();

    float linv[4];
#pragma unroll
    for (int nt = 0; nt < 4; ++nt) linv[nt] = 0.2f / lw[16 * nt + l16];

    float* __restrict__ out2 = out + OUT2_OFF + (size_t)((g << 2) + b) * (256 * 1024);

#pragma unroll
    for (int h = 0; h < 2; ++h) {
        if ((w >> 1) == h) {
            const int we = w & 1;
#pragma unroll
            for (int mt = 0; mt < 4; ++mt)
#pragma unroll
                for (int nt = 0; nt < 4; ++nt)
#pragma unroll
                    for (int r = 0; r < 4; ++r)
                        sm.epi[we][16 * mt + 4 * quad + r][16 * nt + l16] = O[mt][nt][r] * linv[nt];
        }
        __syncthreads();
#pragma unroll 4
        for (int i = 0; i < 32; ++i) {
            const int ro = w * 32 + i;   // 0..127 -> c = 128h + ro
            const float v = sm.epi[ro >> 6][ro & 63][lane];
            atomicAdd(out2 + (size_t)(h * 128 + ro) * 1024 + q0 + lane, v);
        }
        __syncthreads();
    }
}

// ---------------------------------------------------------------------------
extern "C" void kernel_launch(void* const* d_in, const int* in_sizes, int n_in,
                              void* d_out, int out_size, void* d_ws, size_t ws_size,
                              hipStream_t stream) {
    const float* q = (const float*)d_in[0];
    const float* s = (const float*)d_in[1];
    float* out = (float*)d_out;
    float* ws = (float*)d_ws;
    unsigned short* sh = (unsigned short*)((char*)d_ws + WS_SH);
    unsigned short* sv = sh + SH_ELEMS;
    unsigned short* qt = sv + SV_ELEMS;

    hipMemsetAsync(d_ws, 0, 2 * sizeof(float), stream);

    means_kernel<<<256, 256, 0, stream>>>(q, s, ws);
    convert_kernel<<<dim3(32, 8, 14), 256, 0, stream>>>(q, s, ws, sh, sv, qt, out);
    attn_kernel<<<dim3(16, 40), 256, 0, stream>>>(qt, sh, sv, out);
}

// Round 10
// 202.757 us; speedup vs baseline: 1.2971x; 1.0441x over previous
//
#include <hip/hip_runtime.h>

// B=4, N=10, C=256, Lq=Ls=1024, K=5, G=2.  TQ=64, TS=32.  fp16 MFMA path.
#define CQ_ELEMS (4 * 256 * 1024)
#define CS_ELEMS (10 * 256 * 1024)
#define OUT2_OFF 2097152

typedef __attribute__((ext_vector_type(8))) _Float16 f16x8;
typedef __attribute__((ext_vector_type(4))) float f32x4;

// ws layout (bytes): [0..255] float means[2];
//   Sh[n][s][c] fp16, Sv[n][c][s] fp16, Qt[b][q][c] fp16
#define WS_SH 256
#define SH_ELEMS (10 * 1024 * 256)
#define SV_ELEMS (10 * 256 * 1024)

// direct global->LDS DMA, 16 B per lane; LDS dest = wave-uniform base + lane*16
__device__ __forceinline__ void gload_lds16(const unsigned short* g, unsigned short* l) {
    __builtin_amdgcn_global_load_lds(
        (const __attribute__((address_space(1))) void*)g,
        (__attribute__((address_space(3))) void*)l, 16, 0, 0);
}

// ---------------------------------------------------------------------------
__global__ __launch_bounds__(256) void means_kernel(const float* __restrict__ q,
                                                    const float* __restrict__ s,
                                                    float* __restrict__ ws) {
    const int tid = blockIdx.x * 256 + threadIdx.x;
    const int stride = gridDim.x * 256;
    float sq = 0.f, ss = 0.f;
    const float4* q4 = (const float4*)q;
    const float4* s4 = (const float4*)s;
    for (int i = tid; i < CQ_ELEMS / 4; i += stride) {
        float4 v = q4[i];
        sq += (v.x + v.y) + (v.z + v.w);
    }
    for (int i = tid; i < CS_ELEMS / 4; i += stride) {
        float4 v = s4[i];
        ss += (v.x + v.y) + (v.z + v.w);
    }
#pragma unroll
    for (int off = 32; off > 0; off >>= 1) {
        sq += __shfl_down(sq, off, 64);
        ss += __shfl_down(ss, off, 64);
    }
    __shared__ float redq[4], reds[4];
    const int lane = threadIdx.x & 63, wid = threadIdx.x >> 6;
    if (lane == 0) { redq[wid] = sq; reds[wid] = ss; }
    __syncthreads();
    if (threadIdx.x == 0) {
        atomicAdd(&ws[0], (redq[0] + redq[1]) + (redq[2] + redq[3]));
        atomicAdd(&ws[1], (reds[0] + reds[1]) + (reds[2] + reds[3]));
    }
}

// ---------------------------------------------------------------------------
// Centered fp16 conversion.  z<10: S -> Sv [c][s] + Sh [s][c] + zero out2.
// z>=10: Q -> q_out (fp32, both g-copies) + Qt [q][c].
// ---------------------------------------------------------------------------
__global__ __launch_bounds__(256) void convert_kernel(const float* __restrict__ Q,
                                                      const float* __restrict__ S,
                                                      const float* __restrict__ ws,
                                                      unsigned short* __restrict__ sh,
                                                      unsigned short* __restrict__ sv,
                                                      unsigned short* __restrict__ qt,
                                                      float* __restrict__ out) {
    __shared__ unsigned short Th[32][40];
    const int t = threadIdx.x;
    const int x0 = blockIdx.x << 5;   // s (or q) tile base
    const int c0 = blockIdx.y << 5;   // c tile base
    const int z = blockIdx.z;

    const int cl = t >> 3, x4 = (t & 7) << 2;

    if (z < 10) {
        const int n = z;
        const float ms = ws[1] * (1.0f / (float)CS_ELEMS);
        float4 v = *(const float4*)(S + ((size_t)(n * 256 + c0 + cl)) * 1024 + x0 + x4);
        float x[4] = {v.x - ms, v.y - ms, v.z - ms, v.w - ms};
        unsigned short hb[4];
#pragma unroll
        for (int j = 0; j < 4; ++j) {
            _Float16 h = (_Float16)x[j];
            hb[j] = __builtin_bit_cast(unsigned short, h);
            Th[cl][x4 + j] = hb[j];
        }
        *(ushort4*)(sv + ((size_t)(n * 256 + c0 + cl)) * 1024 + x0 + x4) =
            make_ushort4(hb[0], hb[1], hb[2], hb[3]);
        // zero the atomically-accumulated 'aligned' half of d_out (8 MB over 2560 blocks)
        {
            const int lin = (z * 8 + blockIdx.y) * 32 + blockIdx.x;
            const int gid = lin * 256 + t;
            if (gid < 524288) ((int4*)(out + OUT2_OFF))[gid] = make_int4(0, 0, 0, 0);
        }
        __syncthreads();
        const int sl = t >> 3, c4 = (t & 7) << 2;
        *(ushort4*)(sh + ((size_t)(n * 1024 + x0 + sl)) * 256 + c0 + c4) =
            make_ushort4(Th[c4 + 0][sl], Th[c4 + 1][sl], Th[c4 + 2][sl], Th[c4 + 3][sl]);
    } else {
        const int b = z - 10;
        const float mq = ws[0] * (1.0f / (float)CQ_ELEMS);
        float4 v = *(const float4*)(Q + ((size_t)(b * 256 + c0 + cl)) * 1024 + x0 + x4);
        v.x -= mq; v.y -= mq; v.z -= mq; v.w -= mq;
        float* o = out + ((size_t)(b * 2) * 256 + (c0 + cl)) * 1024 + x0 + x4;
        *(float4*)o = v;
        *(float4*)(o + 256 * 1024) = v;
        float x[4] = {v.x, v.y, v.z, v.w};
#pragma unroll
        for (int j = 0; j < 4; ++j) {
            _Float16 h = (_Float16)x[j];
            Th[cl][x4 + j] = __builtin_bit_cast(unsigned short, h);
        }
        __syncthreads();
        const int ql = t >> 3, c4 = (t & 7) << 2;
        *(ushort4*)(qt + ((size_t)(b * 1024 + x0 + ql)) * 256 + c0 + c4) =
            make_ushort4(Th[c4 + 0][ql], Th[c4 + 1][ql], Th[c4 + 2][ql], Th[c4 + 3][ql]);
    }
}

// ---------------------------------------------------------------------------
// Fused flash attention, fp16 MFMA.  R8 structure (3 blocks/CU, s1 DMA
// double-buffer, s2 eliminated, 2 barriers/step) with the V^T frag loads
// issued at the TOP of the step (independent of P): their L2 latency
// overlaps QK^T+softmax and B2's vmcnt(0) drain guarantees residency
// before PV -> removes R8's post-B2 VMEM stall.
// s1 frag-major: slot16 = fidx*64 + quad*16 + l16 (fidx=2f+nt) holds
//   Sh[s0+2*l16+nt][f*32+quad*8..+7]; frag reads consecutive-lane -> cf.
// No cross-barrier read-write register arrays (R4/R5 spill lesson;
// read-only frags like qf/vf are fine).
// NOTE R9: hipLaunchCooperativeKernel fails under this harness's graph
// capture -> stay with 3 plain dispatches.
// ---------------------------------------------------------------------------
union __align__(16) SMem {
    struct {
        unsigned short s1[2][8192];  // 32 KB, frag-major QK B-tiles (dbuf)
        unsigned short pb[64][40];   // 5 KB, P [q][s] 80 B rows
    } st;
    float epi[2][64][68];            // 34816 B, aliases st at epilogue
};

__global__ __launch_bounds__(256, 3) void attn_kernel(const unsigned short* __restrict__ qt,
                                                      const unsigned short* __restrict__ sh,
                                                      const unsigned short* __restrict__ sv,
                                                      float* __restrict__ out) {
    __shared__ SMem sm;
    __shared__ float aw[64];   // per-step alpha (cross-wave, read after B2)
    __shared__ float lw[64];   // final l

    const int t = threadIdx.x;
    const int w = t >> 6;
    const int lane = t & 63;
    const int quad = lane >> 4;
    const int l16 = lane & 15;

    const int q0 = blockIdx.x << 6;   // 16 q-tiles
    const int bn = blockIdx.y;        // 40
    const int b = bn / 10;
    const int n = bn - b * 10;
    const int g = n / 5;

    const unsigned short* __restrict__ Shn = sh + (size_t)n * (1024 * 256);
    const unsigned short* __restrict__ Svn = sv + (size_t)n * (256 * 1024);

    // ---- Q A-frags: wave w owns q rows q0+16w .. +15 ----
    f16x8 qf[8];
    {
        const unsigned short* qp = qt + (size_t)(b * 1024 + q0 + 16 * w + l16) * 256 + quad * 8;
#pragma unroll
        for (int f = 0; f < 8; ++f)
            qf[f] = *(const f16x8*)(qp + f * 32);
    }

    // V^T frag base pointers (step-invariant): c = 64w + 16mt + l16, chunk quad
    const unsigned short* vbase[4];
#pragma unroll
    for (int mt = 0; mt < 4; ++mt)
        vbase[mt] = Svn + (size_t)(64 * w + 16 * mt + l16) * 1024 + quad * 8;

    f32x4 O[4][4];   // O^T: c = 64w+16mt+4quad+r, q = 16nt+l16
#pragma unroll
    for (int mt = 0; mt < 4; ++mt)
#pragma unroll
        for (int nt = 0; nt < 4; ++nt) O[mt][nt] = (f32x4){0.f, 0.f, 0.f, 0.f};

    float m_run[4], l_run[4];
#pragma unroll
    for (int r = 0; r < 4; ++r) { m_run[r] = -1e30f; l_run[r] = 0.f; }

    // ---- s1 DMA staging for one step into buffer buf_ ----
#define STAGE1(s0_, buf_)                                                                  \
    {                                                                                      \
        const int s0v = (s0_);                                                             \
        _Pragma("unroll")                                                                  \
        for (int j = 0; j < 4; ++j) {                                                      \
            const int fidx = 4 * w + j;                                                    \
            const unsigned short* g1 = Shn +                                               \
                (size_t)(s0v + 2 * l16 + (fidx & 1)) * 256 + (fidx >> 1) * 32 + quad * 8;  \
            gload_lds16(g1, &sm.st.s1[buf_][fidx * 512]);                                  \
        }                                                                                  \
    }

    STAGE1(0, 0);

    for (int s0i = 0; s0i < 32; ++s0i) {
        const int cur = s0i & 1;
        const int s0 = s0i << 5;
        __syncthreads();   // B1: drains DMA into s1[cur]; all reads of s1[cur^1] done

        if (s0i < 31) STAGE1((s0i + 1) << 5, cur ^ 1);   // hidden behind QK+softmax

        // ---- EARLY V^T frag loads (independent of P; resident by B2's drain) ----
        f16x8 vf[4];
#pragma unroll
        for (int mt = 0; mt < 4; ++mt)
            vf[mt] = *(const f16x8*)(vbase[mt] + s0);

        // ---- QK^T: sim[16q x 32s], q rows 16w+4quad+r ----
        f32x4 sim0 = (f32x4){0.f, 0.f, 0.f, 0.f};
        f32x4 sim1 = (f32x4){0.f, 0.f, 0.f, 0.f};
#pragma unroll
        for (int f = 0; f < 8; ++f) {
            const unsigned short* base = &sm.st.s1[cur][f * 1024 + quad * 128 + l16 * 8];
            f16x8 b0 = *(const f16x8*)base;           // nt=0: true s = 2*l16
            f16x8 b1 = *(const f16x8*)(base + 512);   // nt=1: true s = 2*l16+1
            sim0 = __builtin_amdgcn_mfma_f32_16x16x32_f16(qf[f], b0, sim0, 0, 0, 0);
            sim1 = __builtin_amdgcn_mfma_f32_16x16x32_f16(qf[f], b1, sim1, 0, 0, 0);
        }

        // ---- online softmax (reduce over the 16 l16 lanes) ----
        float rowmax[4];
#pragma unroll
        for (int r = 0; r < 4; ++r) rowmax[r] = fmaxf(sim0[r], sim1[r]);
#pragma unroll
        for (int off = 1; off <= 8; off <<= 1)
#pragma unroll
            for (int r = 0; r < 4; ++r)
                rowmax[r] = fmaxf(rowmax[r], __shfl_xor(rowmax[r], off, 64));

        float al[4], rs[4], pv0[4], pv1[4];
#pragma unroll
        for (int r = 0; r < 4; ++r) {
            const float mn = fmaxf(m_run[r], rowmax[r]);
            al[r] = __expf(m_run[r] - mn);
            m_run[r] = mn;
            pv0[r] = __expf(sim0[r] - mn);
            pv1[r] = __expf(sim1[r] - mn);
            rs[r] = pv0[r] + pv1[r];
        }
#pragma unroll
        for (int off = 1; off <= 8; off <<= 1)
#pragma unroll
            for (int r = 0; r < 4; ++r) rs[r] += __shfl_xor(rs[r], off, 64);
#pragma unroll
        for (int r = 0; r < 4; ++r) l_run[r] = l_run[r] * al[r] + rs[r];

        // ---- publish P (fp16 pairs, b32) and alpha ----
#pragma unroll
        for (int r = 0; r < 4; ++r) {
            union { _Float16 h[2]; unsigned u; } pk;
            pk.h[0] = (_Float16)pv0[r];
            pk.h[1] = (_Float16)pv1[r];
            *(unsigned*)&sm.st.pb[16 * w + 4 * quad + r][l16 * 2] = pk.u;
        }
        if (l16 == 0) {
#pragma unroll
            for (int r = 0; r < 4; ++r) aw[16 * w + 4 * quad + r] = al[r];
        }
        __syncthreads();   // B2: P/alpha visible; also drains vf + next-step DMA

        // ---- rescale O^T, then O^T += V^T * P^T ----
#pragma unroll
        for (int nt = 0; nt < 4; ++nt) {
            const float a = aw[16 * nt + l16];
#pragma unroll
            for (int mt = 0; mt < 4; ++mt) {
                O[mt][nt][0] *= a; O[mt][nt][1] *= a; O[mt][nt][2] *= a; O[mt][nt][3] *= a;
            }
        }
        f16x8 pf[4];
#pragma unroll
        for (int nt = 0; nt < 4; ++nt)
            pf[nt] = *(const f16x8*)&sm.st.pb[16 * nt + l16][quad * 8];
#pragma unroll
        for (int mt = 0; mt < 4; ++mt)
#pragma unroll
            for (int nt = 0; nt < 4; ++nt)
                O[mt][nt] = __builtin_amdgcn_mfma_f32_16x16x32_f16(vf[mt], pf[nt], O[mt][nt], 0, 0, 0);
    }

    // ---- epilogue ----
    if (l16 == 0) {
#pragma unroll
        for (int r = 0; r < 4; ++r) lw[16 * w + 4 * quad + r] = l_run[r];
    }
    __syncthreads();

    float linv[4];
#pragma unroll
    for (int nt = 0; nt < 4; ++nt) linv[nt] = 0.2f / lw[16 * nt + l16];

    float* __restrict__ out2 = out + OUT2_OFF + (size_t)((g << 2) + b) * (256 * 1024);

#pragma unroll
    for (int h = 0; h < 2; ++h) {
        if ((w >> 1) == h) {
            const int we = w & 1;
#pragma unroll
            for (int mt = 0; mt < 4; ++mt)
#pragma unroll
                for (int nt = 0; nt < 4; ++nt)
#pragma unroll
                    for (int r = 0; r < 4; ++r)
                        sm.epi[we][16 * mt + 4 * quad + r][16 * nt + l16] = O[mt][nt][r] * linv[nt];
        }
        __syncthreads();
#pragma unroll 4
        for (int i = 0; i < 32; ++i) {
            const int ro = w * 32 + i;   // 0..127 -> c = 128h + ro
            const float v = sm.epi[ro >> 6][ro & 63][lane];
            atomicAdd(out2 + (size_t)(h * 128 + ro) * 1024 + q0 + lane, v);
        }
        __syncthreads();
    }
}

// ---------------------------------------------------------------------------
extern "C" void kernel_launch(void* const* d_in, const int* in_sizes, int n_in,
                              void* d_out, int out_size, void* d_ws, size_t ws_size,
                              hipStream_t stream) {
    const float* q = (const float*)d_in[0];
    const float* s = (const float*)d_in[1];
    float* out = (float*)d_out;
    float* ws = (float*)d_ws;
    unsigned short* sh = (unsigned short*)((char*)d_ws + WS_SH);
    unsigned short* sv = sh + SH_ELEMS;
    unsigned short* qt = sv + SV_ELEMS;

    hipMemsetAsync(d_ws, 0, 2 * sizeof(float), stream);

    means_kernel<<<256, 256, 0, stream>>>(q, s, ws);
    convert_kernel<<<dim3(32, 8, 14), 256, 0, stream>>>(q, s, ws, sh, sv, qt, out);
    attn_kernel<<<dim3(16, 40), 256, 0, stream>>>(qt, sh, sv, out);
}